// Round 1
// baseline (17915.741 us; speedup 1.0000x reference)
//
#include <hip/hip_runtime.h>
#include <math.h>

#define BB 64
#define TT 1024
#define HC 512
#define HSZ 512
#define VV 64
#define HM 128
#define KX 576        // VV + HC
#define F1 1024       // HSZ + HC
#define NSTEP 128
#define EPSV 1e-5f

// workspace offsets (in floats)
#define OFF_X     0         // [64][576]
#define OFF_HS0   36864     // [64][512]
#define OFF_HS1   69632     // [64][512]
#define OFF_CS    102400    // [64][512]
#define OFF_E     135168    // [64][1024]
#define OFF_A     200704    // [64][1024]
#define OFF_CTX   266240    // [64][512]
#define OFF_PBMAX 299008    // [4096]
#define OFF_LENS  303104    // [64] int

// output offsets (floats)
#define OUT_YH    0                    // [64][128][64]
#define OUT_LENS  524288               // [64]
#define OUT_ATT   524352               // [64][128][1024]

__device__ __forceinline__ float sigf(float x) { return 1.0f / (1.0f + __expf(-x)); }
__device__ __forceinline__ float dot4(float4 a, float4 b) {
    return a.x * b.x + a.y * b.y + a.z * b.z + a.w * b.w;
}

// init: x0 = [onehot(SOS=0), h[:,0,:]], hs=0, cs=0, lens=128
__global__ void k_init(const float* __restrict__ h, float* __restrict__ ws) {
    int tid = blockIdx.x * 256 + threadIdx.x;   // grid 256x256 = 65536
    if (tid < BB * KX) {
        int b = tid / KX, k = tid % KX;
        float v = 0.0f;
        if (k == 0) v = 1.0f;
        else if (k >= VV) v = h[(size_t)b * TT * HC + (k - VV)];
        ws[OFF_X + tid] = v;
    }
    if (tid < BB * HSZ) {
        ws[OFF_HS0 + tid] = 0.0f;
        ws[OFF_CS + tid] = 0.0f;
    }
    if (tid < BB) ((int*)ws)[OFF_LENS + tid] = NSTEP;
}

// gates GEMM + LSTM cell. p = step parity: hs_in = HS[p], hs_out = HS[1-p].
// grid 256 blocks x 256 threads. Per block: 2 units; per thread: 2 gate rows, all-64-b per wave lane.
__global__ void k_gates(const float* __restrict__ Wih, const float* __restrict__ Whh,
                        const float* __restrict__ bih, const float* __restrict__ bhh,
                        float* __restrict__ ws, int p) {
    int tid = threadIdx.x;
    int b = tid & 63;
    int half = (tid >> 6) & 1;              // 0: rows (i,f)  1: rows (g,o)
    int u = blockIdx.x * 2 + (tid >> 7);    // unit in [0,512)
    int r0 = half * 2 * HSZ + u;            // i or g
    int r1 = r0 + HSZ;                      // f or o
    const float* xr = ws + OFF_X + b * KX;
    const float* hr = ws + (p ? OFF_HS1 : OFF_HS0) + b * HSZ;
    float a0 = bih[r0] + bhh[r0];
    float a1 = bih[r1] + bhh[r1];
    {
        const float4* x4 = (const float4*)xr;
        const float4* w0 = (const float4*)(Wih + (size_t)r0 * KX);
        const float4* w1 = (const float4*)(Wih + (size_t)r1 * KX);
#pragma unroll 4
        for (int k = 0; k < KX / 4; k++) {
            float4 xv = x4[k];
            a0 += dot4(w0[k], xv);
            a1 += dot4(w1[k], xv);
        }
    }
    {
        const float4* h4 = (const float4*)hr;
        const float4* w0 = (const float4*)(Whh + (size_t)r0 * HSZ);
        const float4* w1 = (const float4*)(Whh + (size_t)r1 * HSZ);
#pragma unroll 4
        for (int k = 0; k < HSZ / 4; k++) {
            float4 hv = h4[k];
            a0 += dot4(w0[k], hv);
            a1 += dot4(w1[k], hv);
        }
    }
    __shared__ float g0s[256], g1s[256];
    g0s[tid] = a0;
    g1s[tid] = a1;
    __syncthreads();
    if (half == 0) {
        float gi = g0s[tid], gf = g1s[tid];
        float gg = g0s[tid + 64], go = g1s[tid + 64];
        int idx = b * HSZ + u;
        float co = ws[OFF_CS + idx];
        float I = sigf(gi), F = sigf(gf), G = tanhf(gg), O = sigf(go);
        float cn = F * co + I * G;
        ws[OFF_CS + idx] = cn;
        ws[(p ? OFF_HS0 : OFF_HS1) + idx] = O * tanhf(cn);
    }
}

// e[b,t] = <hs_new[b], h[b,t,:]>; per-block max -> PBMAX.
// grid 4096 (b*64 + tgroup), block 1024 (16 waves, one t per wave)
__global__ void k_escore(const float* __restrict__ h, float* __restrict__ ws, int p) {
    int blk = blockIdx.x;
    int b = blk >> 6, tg = blk & 63;
    int w = threadIdx.x >> 6, lane = threadIdx.x & 63;
    int t = tg * 16 + w;
    const float4* h4 = (const float4*)(h + ((size_t)b * TT + t) * HC);
    const float4* s4 = (const float4*)(ws + (p ? OFF_HS0 : OFF_HS1) + b * HSZ);
    float part = dot4(h4[lane], s4[lane]) + dot4(h4[64 + lane], s4[64 + lane]);
#pragma unroll
    for (int m = 1; m < 64; m <<= 1) part += __shfl_xor(part, m);
    __shared__ float sm[16];
    if (lane == 0) {
        ws[OFF_E + b * TT + t] = part;
        sm[w] = part;
    }
    __syncthreads();
    if (threadIdx.x == 0) {
        float mx = sm[0];
#pragma unroll
        for (int i = 1; i < 16; i++) mx = fmaxf(mx, sm[i]);
        ws[OFF_PBMAX + blk] = mx;
    }
}

// global max over PBMAX, masked softmax with +EPS denominator, write a + attentions out.
// grid 64 (b), block 256
__global__ void k_soft(const int* __restrict__ slen, float* __restrict__ ws,
                       float* __restrict__ out, int ts) {
    int b = blockIdx.x, tid = threadIdx.x;
    __shared__ float red[256];
    float mx = -INFINITY;
    for (int i = tid; i < 4096; i += 256) mx = fmaxf(mx, ws[OFF_PBMAX + i]);
    red[tid] = mx;
    __syncthreads();
    for (int s = 128; s > 0; s >>= 1) {
        if (tid < s) red[tid] = fmaxf(red[tid], red[tid + s]);
        __syncthreads();
    }
    float m = red[0];
    __syncthreads();
    int L = slen[b];
    float ex[4];
    float loc = 0.0f;
#pragma unroll
    for (int q = 0; q < 4; q++) {
        int t = tid + 256 * q;
        float v = (t < L) ? __expf(ws[OFF_E + b * TT + t] - m) : 0.0f;
        ex[q] = v;
        loc += v;
    }
    red[tid] = loc;
    __syncthreads();
    for (int s = 128; s > 0; s >>= 1) {
        if (tid < s) red[tid] += red[tid + s];
        __syncthreads();
    }
    float inv = 1.0f / (red[0] + EPSV);
#pragma unroll
    for (int q = 0; q < 4; q++) {
        int t = tid + 256 * q;
        float a = ex[q] * inv;
        ws[OFF_A + b * TT + t] = a;
        out[OUT_ATT + (size_t)b * (NSTEP * TT) + (size_t)ts * TT + t] = a;
    }
}

// ctx[b,:] = sum_t a[b,t] * h[b,t,:]
// grid 256 (b*4 + dchunk of 128), block 256 = 8 t-groups x 32 lanes (float4 each)
__global__ void k_ctx(const float* __restrict__ h, float* __restrict__ ws) {
    int blk = blockIdx.x;
    int b = blk >> 2, ch = blk & 3;
    int grp = threadIdx.x >> 5, lane = threadIdx.x & 31;
    int d0 = ch * 128;
    const float* hb = h + (size_t)b * TT * HC + d0 + lane * 4;
    const float* ar = ws + OFF_A + b * TT;
    float4 acc = {0.0f, 0.0f, 0.0f, 0.0f};
    for (int t = grp; t < TT; t += 8) {
        float av = ar[t];
        float4 hv = *(const float4*)(hb + (size_t)t * HC);
        acc.x += av * hv.x;
        acc.y += av * hv.y;
        acc.z += av * hv.z;
        acc.w += av * hv.w;
    }
    __shared__ float4 red4[8][32];
    red4[grp][lane] = acc;
    __syncthreads();
    if (threadIdx.x < 128) {
        const float* rf = (const float*)red4;
        float s = 0.0f;
#pragma unroll
        for (int g2 = 0; g2 < 8; g2++) s += rf[g2 * 128 + threadIdx.x];
        ws[OFF_CTX + b * HSZ + d0 + threadIdx.x] = s;
    }
}

// head: feat=[hs,ctx] -> fc1 -> fc2 -> softmax -> y_hat; lens update; x=[y_hat,ctx]
// grid 64 (b), block 256
__global__ void k_out(const float* __restrict__ fc1w, const float* __restrict__ fc1b,
                      const float* __restrict__ fc2w, float* __restrict__ ws,
                      float* __restrict__ out, int p, int ts) {
    int b = blockIdx.x, tid = threadIdx.x;
    __shared__ float feat[F1];
    __shared__ float m1[HM];
    __shared__ float l2[VV];
    const float* hsr = ws + (p ? OFF_HS0 : OFF_HS1) + b * HSZ;
    const float* cr = ws + OFF_CTX + b * HSZ;
#pragma unroll
    for (int q = 0; q < 4; q++) {
        int i = tid + 256 * q;
        feat[i] = (i < HSZ) ? hsr[i] : cr[i - HSZ];
    }
    __syncthreads();
    if (tid < HM) {
        const float4* w4 = (const float4*)(fc1w + (size_t)tid * F1);
        const float4* f4 = (const float4*)feat;
        float acc = fc1b[tid];
        for (int k = 0; k < F1 / 4; k++) acc += dot4(w4[k], f4[k]);
        m1[tid] = acc;
    }
    __syncthreads();
    if (tid < VV) {
        const float4* w4 = (const float4*)(fc2w + (size_t)tid * HM);
        const float4* f4 = (const float4*)m1;
        float acc = 0.0f;
#pragma unroll
        for (int k = 0; k < HM / 4; k++) acc += dot4(w4[k], f4[k]);
        l2[tid] = acc;
    }
    __syncthreads();
    if (tid < VV) {
        float v = l2[tid];
        float mx = v;
#pragma unroll
        for (int m = 1; m < 64; m <<= 1) mx = fmaxf(mx, __shfl_xor(mx, m));
        float ev = __expf(v - mx);
        float s = ev;
#pragma unroll
        for (int m = 1; m < 64; m <<= 1) s += __shfl_xor(s, m);
        float y = ev / s;
        out[OUT_YH + (size_t)b * (NSTEP * VV) + ts * VV + tid] = y;
        ws[OFF_X + b * KX + tid] = y;
        // argmax, first-index tie-break
        float av = v;
        int ai = tid;
#pragma unroll
        for (int m = 1; m < 64; m <<= 1) {
            float ov = __shfl_xor(av, m);
            int oi = __shfl_xor(ai, m);
            if (ov > av || (ov == av && oi < ai)) { av = ov; ai = oi; }
        }
        if (tid == 0) {
            int* lens = (int*)ws + OFF_LENS;
            if (ai == 1 && lens[b] > ts) lens[b] = ts + 1;   // EOS == 1
        }
    }
#pragma unroll
    for (int q = 0; q < 2; q++) {
        int i = tid + 256 * q;
        if (i < HSZ) ws[OFF_X + b * KX + VV + i] = cr[i];
    }
}

__global__ void k_lens(const float* __restrict__ ws, float* __restrict__ out) {
    int tid = threadIdx.x;   // 64
    out[OUT_LENS + tid] = (float)(((const int*)ws)[OFF_LENS + tid]);
}

extern "C" void kernel_launch(void* const* d_in, const int* in_sizes, int n_in,
                              void* d_out, int out_size, void* d_ws, size_t ws_size,
                              hipStream_t stream) {
    (void)in_sizes; (void)n_in; (void)out_size; (void)ws_size;
    const float* h    = (const float*)d_in[0];
    const float* Wih  = (const float*)d_in[1];
    const float* Whh  = (const float*)d_in[2];
    const float* bih  = (const float*)d_in[3];
    const float* bhh  = (const float*)d_in[4];
    const float* fc1w = (const float*)d_in[5];
    const float* fc1b = (const float*)d_in[6];
    const float* fc2w = (const float*)d_in[7];
    const int*   slen = (const int*)d_in[8];
    float* ws  = (float*)d_ws;
    float* out = (float*)d_out;

    k_init<<<256, 256, 0, stream>>>(h, ws);
    for (int t = 0; t < NSTEP; t++) {
        int p = t & 1;
        k_gates<<<256, 256, 0, stream>>>(Wih, Whh, bih, bhh, ws, p);
        k_escore<<<4096, 1024, 0, stream>>>(h, ws, p);
        k_soft<<<64, 256, 0, stream>>>(slen, ws, out, t);
        k_ctx<<<256, 256, 0, stream>>>(h, ws);
        k_out<<<64, 256, 0, stream>>>(fc1w, fc1b, fc2w, ws, out, p, t);
    }
    k_lens<<<1, 64, 0, stream>>>(ws, out);
}

// Round 2
// 12384.631 us; speedup vs baseline: 1.4466x; 1.4466x over previous
//
#include <hip/hip_runtime.h>
#include <math.h>

#define BB 64
#define TT 1024
#define HC 512
#define HSZ 512
#define VV 64
#define HM 128
#define KX 576          // VV + HC
#define KTOT 1088       // KX + HSZ
#define NSTEP 128
#define EPSV 1e-5f

// workspace offsets (floats)
#define OFF_XT   0          // XT[1088][64]: rows 0..575 = x^T, rows 576..1087 = hs^T
#define OFF_CS   69632      // csT[512][64]
#define OFF_E    102400     // e[64][1024]
#define OFF_PB   167936     // per-block maxes [1024]
#define OFF_LENS 168960     // int lens[64]
#define OFF_W2   169024     // W2[64][1024] = fc2w @ fc1w
#define OFF_B2   234560     // b2[64] = fc2w @ fc1b
#define OFF_GP   234624     // gate partials [8 kc][4 g][512 u][64 b]
#define OFF_CP   1283200    // ctx partials [64 b][16 tc][512 d]
// total = 1807488 floats = 7.23 MB

// output offsets (floats)
#define OUT_YH   0          // [64][128][64]
#define OUT_LENS 524288     // [64]
#define OUT_ATT  524352     // [64][128][1024]

__device__ __forceinline__ float sigf(float x) { return 1.0f / (1.0f + __expf(-x)); }
__device__ __forceinline__ float dot4(float4 a, float4 b) {
    return a.x * b.x + a.y * b.y + a.z * b.z + a.w * b.w;
}

// ---------------- init ----------------
__global__ void k_init(const float* __restrict__ h, float* __restrict__ ws) {
    int idx = blockIdx.x * 256 + threadIdx.x;   // grid 512x256
    if (idx < KTOT * BB) {
        int k = idx >> 6, b = idx & 63;
        float v = 0.0f;
        if (k == 0) v = 1.0f;                                    // one-hot SOS
        else if (k >= VV && k < KX) v = h[(size_t)b * TT * HC + (k - VV)];
        ws[OFF_XT + idx] = v;                                    // rows >= 576 (hs) = 0
    }
    if (idx < HSZ * BB) ws[OFF_CS + idx] = 0.0f;
    if (idx < BB) ((int*)ws)[OFF_LENS + idx] = NSTEP;
}

// ---------------- fc2 o fc1 composition (once per launch) ----------------
__global__ void k_fuse(const float* __restrict__ fc1w, const float* __restrict__ fc1b,
                       const float* __restrict__ fc2w, float* __restrict__ ws) {
    int blk = blockIdx.x;            // 256 blocks: v = blk>>2, kc = blk&3
    int v = blk >> 2, kc = blk & 3;
    int k = kc * 256 + threadIdx.x;
    float acc = 0.0f;
#pragma unroll 8
    for (int m = 0; m < HM; m++) acc += fc2w[v * HM + m] * fc1w[(size_t)m * 1024 + k];
    ws[OFF_W2 + (size_t)v * 1024 + k] = acc;
    if (kc == 0 && threadIdx.x == 0) {
        float bb = 0.0f;
        for (int m = 0; m < HM; m++) bb += fc2w[v * HM + m] * fc1b[m];
        ws[OFF_B2 + v] = bb;
    }
}

// ---------------- gates GEMM partials ----------------
// grid 1024 = 128 ugroups x 8 kchunks, block 256 = 4 waves (one u per wave)
// wave computes rows {u, 512+u, 1024+u, 1536+u} over its K-chunk for all 64 b.
__global__ void k_gates(const float* __restrict__ Wih, const float* __restrict__ Whh,
                        float* __restrict__ ws) {
    int blk = blockIdx.x;
    int ug = blk >> 3, kc = blk & 7;
    int uu = __builtin_amdgcn_readfirstlane(threadIdx.x >> 6);
    int b = threadIdx.x & 63;
    int u = ug * 4 + uu;
    const float* W;
    int k0, klen, ldw, xoff;
    if (kc < 4) { W = Wih; k0 = kc * 144; klen = 144; ldw = KX;  xoff = k0; }
    else        { W = Whh; k0 = (kc - 4) * 128; klen = 128; ldw = HSZ; xoff = KX + k0; }
    const float* w0 = W + (size_t)u * ldw + k0;
    const float* w1 = W + (size_t)(512 + u) * ldw + k0;
    const float* w2 = W + (size_t)(1024 + u) * ldw + k0;
    const float* w3 = W + (size_t)(1536 + u) * ldw + k0;
    const float* xp = ws + OFF_XT + (size_t)xoff * 64 + b;
    float a0 = 0.0f, a1 = 0.0f, a2 = 0.0f, a3 = 0.0f;
#pragma unroll 4
    for (int k = 0; k < klen; k++) {
        float xv = xp[(size_t)k * 64];
        a0 += w0[k] * xv;
        a1 += w1[k] * xv;
        a2 += w2[k] * xv;
        a3 += w3[k] * xv;
    }
    float* gp = ws + OFF_GP + (size_t)kc * 131072 + (size_t)u * 64 + b;
    gp[0] = a0;
    gp[32768] = a1;
    gp[65536] = a2;
    gp[98304] = a3;
}

// ---------------- combine partials + LSTM cell ----------------
// grid 128 x 256: thread = (u, b)
__global__ void k_cell(const float* __restrict__ bih, const float* __restrict__ bhh,
                       float* __restrict__ ws) {
    int tid = threadIdx.x;
    int u = blockIdx.x * 4 + (tid >> 6);
    int b = tid & 63;
    float g4[4];
#pragma unroll
    for (int g = 0; g < 4; g++) {
        const float* gp = ws + OFF_GP + (size_t)g * 32768 + (size_t)u * 64 + b;
        float s = 0.0f;
#pragma unroll
        for (int kc = 0; kc < 8; kc++) s += gp[(size_t)kc * 131072];
        g4[g] = s + bih[g * 512 + u] + bhh[g * 512 + u];
    }
    int idx = u * 64 + b;
    float co = ws[OFF_CS + idx];
    float I = sigf(g4[0]), F = sigf(g4[1]), G = tanhf(g4[2]), O = sigf(g4[3]);
    float cn = F * co + I * G;
    ws[OFF_CS + idx] = cn;
    ws[OFF_XT + (size_t)(KX + u) * 64 + b] = O * tanhf(cn);   // hs^T into XT rows 576+
}

// ---------------- e scores + per-block max ----------------
// grid 1024 = b*16 + tc, block 256 = 4 waves; wave w handles 16 t-rows
__global__ void k_escore(const float* __restrict__ h, float* __restrict__ ws) {
    int blk = blockIdx.x;
    int b = blk >> 4, tc = blk & 15;
    int w = threadIdx.x >> 6, lane = threadIdx.x & 63;
    float hsv[8];
#pragma unroll
    for (int j = 0; j < 8; j++)
        hsv[j] = ws[OFF_XT + (size_t)(KX + lane * 8 + j) * 64 + b];
    const float4* h4 = (const float4*)(h + ((size_t)b * TT + tc * 64 + w * 16) * HC);
    float rmax = -INFINITY;
    __shared__ float smax[4];
#pragma unroll 4
    for (int i = 0; i < 16; i++) {
        float4 p = h4[(size_t)i * 128 + lane * 2];
        float4 q = h4[(size_t)i * 128 + lane * 2 + 1];
        float part = p.x * hsv[0] + p.y * hsv[1] + p.z * hsv[2] + p.w * hsv[3]
                   + q.x * hsv[4] + q.y * hsv[5] + q.z * hsv[6] + q.w * hsv[7];
#pragma unroll
        for (int mm = 1; mm < 64; mm <<= 1) part += __shfl_xor(part, mm);
        if (lane == 0) ws[OFF_E + (size_t)b * TT + tc * 64 + w * 16 + i] = part;
        rmax = fmaxf(rmax, part);
    }
    if (lane == 0) smax[w] = rmax;
    __syncthreads();
    if (threadIdx.x == 0)
        ws[OFF_PB + blk] = fmaxf(fmaxf(smax[0], smax[1]), fmaxf(smax[2], smax[3]));
}

// ---------------- global max + masked softmax + attention out + ctx partials ----
// grid 1024 = b*16 + tc, block 256
__global__ void k_actx(const float* __restrict__ h, const int* __restrict__ slen,
                       float* __restrict__ ws, float* __restrict__ out, int ts) {
    int blk = blockIdx.x;
    int b = blk >> 4, tc = blk & 15;
    int tid = threadIdx.x;
    __shared__ float red[256];
    __shared__ float a_sh[64];
    // global max over all (b,t)
    float mx = -INFINITY;
#pragma unroll
    for (int i = 0; i < 4; i++) mx = fmaxf(mx, ws[OFF_PB + tid + 256 * i]);
    red[tid] = mx;
    __syncthreads();
    for (int s = 128; s > 0; s >>= 1) {
        if (tid < s) red[tid] = fmaxf(red[tid], red[tid + s]);
        __syncthreads();
    }
    float m = red[0];
    __syncthreads();
    int L = slen[b];
    float loc = 0.0f;
#pragma unroll
    for (int q = 0; q < 4; q++) {
        int t = tid + 256 * q;
        float e = ws[OFF_E + (size_t)b * TT + t];
        loc += (t < L) ? __expf(e - m) : 0.0f;
    }
    red[tid] = loc;
    __syncthreads();
    for (int s = 128; s > 0; s >>= 1) {
        if (tid < s) red[tid] += red[tid + s];
        __syncthreads();
    }
    float inv = 1.0f / (red[0] + EPSV);
    if (tid < 64) {
        int t = tc * 64 + tid;
        float e = ws[OFF_E + (size_t)b * TT + t];
        float a = (t < L) ? __expf(e - m) * inv : 0.0f;
        a_sh[tid] = a;
        out[OUT_ATT + (size_t)b * (NSTEP * TT) + (size_t)ts * TT + t] = a;
    }
    __syncthreads();
    int d = tid * 2;
    const float* hb = h + ((size_t)b * TT + tc * 64) * HC + d;
    float cx = 0.0f, cy = 0.0f;
#pragma unroll 4
    for (int i = 0; i < 64; i++) {
        float av = a_sh[i];
        float2 hv = *(const float2*)(hb + (size_t)i * HC);
        cx += av * hv.x;
        cy += av * hv.y;
    }
    float* cp = ws + OFF_CP + (size_t)(b * 16 + tc) * 512 + d;
    cp[0] = cx;
    cp[1] = cy;
}

// ---------------- ctx combine + head (composed W2) + softmax/argmax + x update ---
// grid 64 (b), block 256
__global__ void k_comb(float* __restrict__ ws, float* __restrict__ out, int ts) {
    int b = blockIdx.x, tid = threadIdx.x;
    __shared__ float feat[1024];
    __shared__ float l2s[64];
    int d = tid * 2;
    float cx = 0.0f, cy = 0.0f;
#pragma unroll
    for (int tc = 0; tc < 16; tc++) {
        const float* cp = ws + OFF_CP + (size_t)(b * 16 + tc) * 512 + d;
        cx += cp[0];
        cy += cp[1];
    }
    feat[HSZ + d] = cx;
    feat[HSZ + d + 1] = cy;
    ws[OFF_XT + (size_t)(VV + d) * 64 + b] = cx;        // x^T ctx part
    ws[OFF_XT + (size_t)(VV + d + 1) * 64 + b] = cy;
    feat[d]     = ws[OFF_XT + (size_t)(KX + d) * 64 + b];       // hs
    feat[d + 1] = ws[OFF_XT + (size_t)(KX + d + 1) * 64 + b];
    __syncthreads();
    int v = tid >> 2, q = tid & 3;
    const float4* w4 = (const float4*)(ws + OFF_W2 + (size_t)v * 1024 + q * 256);
    const float4* f4 = (const float4*)feat + q * 64;
    float acc = 0.0f;
#pragma unroll 8
    for (int k = 0; k < 64; k++) acc += dot4(w4[k], f4[k]);
    acc += __shfl_xor(acc, 1);
    acc += __shfl_xor(acc, 2);
    if (q == 0) l2s[v] = acc;
    __syncthreads();
    if (tid < 64) {
        float lg = l2s[tid] + ws[OFF_B2 + tid];
        float mxv = lg;
#pragma unroll
        for (int mm = 1; mm < 64; mm <<= 1) mxv = fmaxf(mxv, __shfl_xor(mxv, mm));
        float ev = __expf(lg - mxv);
        float s = ev;
#pragma unroll
        for (int mm = 1; mm < 64; mm <<= 1) s += __shfl_xor(s, mm);
        float y = ev / s;
        out[OUT_YH + (size_t)b * (NSTEP * VV) + ts * VV + tid] = y;
        ws[OFF_XT + (size_t)tid * 64 + b] = y;          // x^T y_hat part
        float av = lg;
        int ai = tid;
#pragma unroll
        for (int mm = 1; mm < 64; mm <<= 1) {
            float ov = __shfl_xor(av, mm);
            int oi = __shfl_xor(ai, mm);
            if (ov > av || (ov == av && oi < ai)) { av = ov; ai = oi; }
        }
        if (tid == 0) {
            int* lens = (int*)ws + OFF_LENS;
            if (ai == 1 && lens[b] > ts) lens[b] = ts + 1;   // EOS == 1
        }
    }
}

__global__ void k_lens(const float* __restrict__ ws, float* __restrict__ out) {
    int tid = threadIdx.x;   // 64
    out[OUT_LENS + tid] = (float)(((const int*)ws)[OFF_LENS + tid]);
}

extern "C" void kernel_launch(void* const* d_in, const int* in_sizes, int n_in,
                              void* d_out, int out_size, void* d_ws, size_t ws_size,
                              hipStream_t stream) {
    (void)in_sizes; (void)n_in; (void)out_size; (void)ws_size;
    const float* h    = (const float*)d_in[0];
    const float* Wih  = (const float*)d_in[1];
    const float* Whh  = (const float*)d_in[2];
    const float* bih  = (const float*)d_in[3];
    const float* bhh  = (const float*)d_in[4];
    const float* fc1w = (const float*)d_in[5];
    const float* fc1b = (const float*)d_in[6];
    const float* fc2w = (const float*)d_in[7];
    const int*   slen = (const int*)d_in[8];
    float* ws  = (float*)d_ws;
    float* out = (float*)d_out;

    k_init<<<512, 256, 0, stream>>>(h, ws);
    k_fuse<<<256, 256, 0, stream>>>(fc1w, fc1b, fc2w, ws);
    for (int t = 0; t < NSTEP; t++) {
        k_gates<<<1024, 256, 0, stream>>>(Wih, Whh, ws);
        k_cell<<<128, 256, 0, stream>>>(bih, bhh, ws);
        k_escore<<<1024, 256, 0, stream>>>(h, ws);
        k_actx<<<1024, 256, 0, stream>>>(h, slen, ws, out, t);
        k_comb<<<64, 256, 0, stream>>>(ws, out, t);
    }
    k_lens<<<1, 64, 0, stream>>>(ws, out);
}